// Round 1
// baseline (784.045 us; speedup 1.0000x reference)
//
#include <hip/hip_runtime.h>
#include <hip/hip_bf16.h>
#include <cstdint>

// Problem constants (from reference)
#define GN 4096      // N nodes
#define GIN 128      // IN_F
#define GF 64        // OUT_F
#define GH 8         // heads
#define GHF (GH*GF)  // 512

// ---------------- Kernel 1: projection xp = A @ Wp^T ----------------
// A: [N, 128] row-major, Wp: [512, 128] row-major, xp: [N, 512]
__global__ __launch_bounds__(256) void gat_proj(const float* __restrict__ A,
                                                const float* __restrict__ W,
                                                float* __restrict__ xp) {
    __shared__ float As[64][129];
    __shared__ float Ws[64][129];
    const int n0 = blockIdx.x * 64;
    const int j0 = blockIdx.y * 64;
    const int tid = threadIdx.x;
    const float4* A4 = (const float4*)A;
    const float4* W4 = (const float4*)W;
#pragma unroll
    for (int i = 0; i < 8; ++i) {
        int idx = tid + i * 256;          // 0..2047 float4 slots (64 rows x 32 f4)
        int r = idx >> 5, c4 = idx & 31;
        float4 v = A4[(size_t)(n0 + r) * 32 + c4];
        As[r][c4 * 4 + 0] = v.x; As[r][c4 * 4 + 1] = v.y;
        As[r][c4 * 4 + 2] = v.z; As[r][c4 * 4 + 3] = v.w;
        float4 w = W4[(size_t)(j0 + r) * 32 + c4];
        Ws[r][c4 * 4 + 0] = w.x; Ws[r][c4 * 4 + 1] = w.y;
        Ws[r][c4 * 4 + 2] = w.z; Ws[r][c4 * 4 + 3] = w.w;
    }
    __syncthreads();
    const int tx = tid & 15, ty = tid >> 4;
    float acc[4][4] = {};
    for (int k = 0; k < 128; ++k) {
        float a[4], b[4];
#pragma unroll
        for (int i = 0; i < 4; ++i) { a[i] = As[ty * 4 + i][k]; b[i] = Ws[tx * 4 + i][k]; }
#pragma unroll
        for (int i = 0; i < 4; ++i)
#pragma unroll
            for (int j = 0; j < 4; ++j) acc[i][j] = fmaf(a[i], b[j], acc[i][j]);
    }
#pragma unroll
    for (int i = 0; i < 4; ++i)
#pragma unroll
        for (int j = 0; j < 4; ++j)
            xp[(size_t)(n0 + ty * 4 + i) * GHF + (j0 + tx * 4 + j)] = acc[i][j];
}

// ---------------- Kernel 2: ss/st = xp . a_src / a_tgt ----------------
// ss[h][n] = sum_f xp[n, h*64+f] * a_src[h*64+f]
__global__ __launch_bounds__(256) void gat_scores(const float* __restrict__ xp,
                                                  const float* __restrict__ a_src,
                                                  const float* __restrict__ a_tgt,
                                                  float* __restrict__ ss,
                                                  float* __restrict__ st) {
    const int lane = threadIdx.x & 63;
    const int w = threadIdx.x >> 6;
    const int r = blockIdx.x * 4 + w;     // 0..32767
    const int h = r >> 12;                // /4096
    const int n = r & 4095;
    float x = xp[(size_t)n * GHF + h * GF + lane];
    float s1 = x * a_src[h * GF + lane];
    float s2 = x * a_tgt[h * GF + lane];
#pragma unroll
    for (int d = 1; d < 64; d <<= 1) {
        s1 += __shfl_xor(s1, d);
        s2 += __shfl_xor(s2, d);
    }
    if (lane == 0) {
        ss[h * GN + n] = s1;
        st[h * GN + n] = s2;
    }
}

// ---------------- Kernel 3: flash-style attention + aggregate + head-mean + relu ----------------
// Block: 512 threads = 8 waves, wave w = head w. Each block: 16 query rows.
__global__ __launch_bounds__(512) void gat_attn(const float* __restrict__ xp,
                                                const float* __restrict__ ss,
                                                const float* __restrict__ st,
                                                const float* __restrict__ mask,
                                                float* __restrict__ out) {
    const int lane = threadIdx.x & 63;   // = f
    const int h = threadIdx.x >> 6;      // head
    const int q0 = blockIdx.x * 16;

    float acc[16], mx[16], ls[16], ssv[16];
#pragma unroll
    for (int i = 0; i < 16; ++i) {
        acc[i] = 0.f; mx[i] = -1e30f; ls[i] = 0.f;
        ssv[i] = ss[h * GN + q0 + i];
    }

    for (int m0 = 0; m0 < GN; m0 += 64) {
        float stv = st[h * GN + m0 + lane];
        float xpr[64];
#pragma unroll
        for (int j = 0; j < 64; ++j)
            xpr[j] = xp[(size_t)(m0 + j) * GHF + h * GF + lane];

#pragma unroll
        for (int i = 0; i < 16; ++i) {
            float mv = mask[(size_t)(q0 + i) * GN + m0 + lane];
            float t = ssv[i] + stv;
            float sc = fmaxf(t, 0.2f * t) + mv;   // leaky_relu(0.2) then +mask
            // wave max over the 64-key tile
            float tm = sc;
#pragma unroll
            for (int d = 1; d < 64; d <<= 1) tm = fmaxf(tm, __shfl_xor(tm, d));
            float nm = fmaxf(mx[i], tm);
            float al = __expf(mx[i] - nm);
            float p = __expf(sc - nm);
            float psum = p;
#pragma unroll
            for (int d = 1; d < 64; d <<= 1) psum += __shfl_xor(psum, d);
            ls[i] = ls[i] * al + psum;
            mx[i] = nm;
            float a = acc[i] * al;
            // phase 2: acc[f] += p[m] * xp[m, h, f]; broadcast p via readlane
#pragma unroll
            for (int j = 0; j < 64; ++j) {
                int pb = __builtin_amdgcn_readlane(__float_as_int(p), j);
                a = fmaf(__int_as_float(pb), xpr[j], a);
            }
            acc[i] = a;
        }
    }

    // cross-head reduction: mean over 8 heads, relu
    __shared__ float hacc[GH][16][64];
#pragma unroll
    for (int i = 0; i < 16; ++i)
        hacc[h][i][lane] = acc[i] / ls[i];
    __syncthreads();
    for (int e = threadIdx.x; e < 16 * 64; e += 512) {
        int q = e >> 6, f = e & 63;
        float s = 0.f;
#pragma unroll
        for (int hh = 0; hh < GH; ++hh) s += hacc[hh][q][f];
        s *= (1.0f / GH);
        out[(size_t)(q0 + q) * GF + f] = fmaxf(s, 0.f);
    }
}

extern "C" void kernel_launch(void* const* d_in, const int* in_sizes, int n_in,
                              void* d_out, int out_size, void* d_ws, size_t ws_size,
                              hipStream_t stream) {
    const float* A     = (const float*)d_in[0];   // [4096,128]
    const float* mask  = (const float*)d_in[1];   // [4096,4096]
    const float* Wp    = (const float*)d_in[2];   // [512,128]
    const float* a_src = (const float*)d_in[3];   // [8,64]
    const float* a_tgt = (const float*)d_in[4];   // [8,64]
    float* out = (float*)d_out;

    float* xp = (float*)d_ws;                       // 4096*512 floats = 8 MB
    float* ss = xp + (size_t)GN * GHF;              // 8*4096
    float* st = ss + (size_t)GH * GN;               // 8*4096

    gat_proj<<<dim3(GN / 64, GHF / 64), 256, 0, stream>>>(A, Wp, xp);
    gat_scores<<<(GH * GN) / 4, 256, 0, stream>>>(xp, a_src, a_tgt, ss, st);
    gat_attn<<<GN / 16, 512, 0, stream>>>(xp, ss, st, mask, out);
}

// Round 2
// 164.913 us; speedup vs baseline: 4.7543x; 4.7543x over previous
//
#include <hip/hip_runtime.h>
#include <hip/hip_bf16.h>
#include <cstdint>

#define GN 4096      // N nodes
#define GIN 128      // IN_F
#define GF 64        // OUT_F
#define GH 8         // heads
#define GHF (GH*GF)  // 512
#define LOG2E 1.4426950408889634f

typedef __attribute__((ext_vector_type(8))) short short8v;
typedef __attribute__((ext_vector_type(4))) float f32x4;

__device__ __forceinline__ short f2bf(float x) {           // RNE float->bf16
    uint32_t u = __float_as_uint(x);
    uint32_t r = u + 0x7fffu + ((u >> 16) & 1u);
    return (short)(r >> 16);
}
__device__ __forceinline__ float bf2f(short h) {
    return __uint_as_float(((uint32_t)(unsigned short)h) << 16);
}
__device__ __forceinline__ float leaky(float t) { return fmaxf(t, 0.2f * t); }

// ---------------- Kernel 1: projection xp = A @ Wp^T (fp32) ----------------
__global__ __launch_bounds__(256) void gat_proj(const float* __restrict__ A,
                                                const float* __restrict__ W,
                                                float* __restrict__ xp) {
    __shared__ float As[64][129];
    __shared__ float Ws[64][129];
    const int n0 = blockIdx.x * 64;
    const int j0 = blockIdx.y * 64;
    const int tid = threadIdx.x;
    const float4* A4 = (const float4*)A;
    const float4* W4 = (const float4*)W;
#pragma unroll
    for (int i = 0; i < 8; ++i) {
        int idx = tid + i * 256;
        int r = idx >> 5, c4 = idx & 31;
        float4 v = A4[(size_t)(n0 + r) * 32 + c4];
        As[r][c4 * 4 + 0] = v.x; As[r][c4 * 4 + 1] = v.y;
        As[r][c4 * 4 + 2] = v.z; As[r][c4 * 4 + 3] = v.w;
        float4 w = W4[(size_t)(j0 + r) * 32 + c4];
        Ws[r][c4 * 4 + 0] = w.x; Ws[r][c4 * 4 + 1] = w.y;
        Ws[r][c4 * 4 + 2] = w.z; Ws[r][c4 * 4 + 3] = w.w;
    }
    __syncthreads();
    const int tx = tid & 15, ty = tid >> 4;
    float acc[4][4] = {};
    for (int k = 0; k < 128; ++k) {
        float a[4], b[4];
#pragma unroll
        for (int i = 0; i < 4; ++i) { a[i] = As[ty * 4 + i][k]; b[i] = Ws[tx * 4 + i][k]; }
#pragma unroll
        for (int i = 0; i < 4; ++i)
#pragma unroll
            for (int j = 0; j < 4; ++j) acc[i][j] = fmaf(a[i], b[j], acc[i][j]);
    }
#pragma unroll
    for (int i = 0; i < 4; ++i)
#pragma unroll
        for (int j = 0; j < 4; ++j)
            xp[(size_t)(n0 + ty * 4 + i) * GHF + (j0 + tx * 4 + j)] = acc[i][j];
}

// ---------------- Kernel 2: ss/st ----------------
__global__ __launch_bounds__(256) void gat_scores(const float* __restrict__ xp,
                                                  const float* __restrict__ a_src,
                                                  const float* __restrict__ a_tgt,
                                                  float* __restrict__ ss,
                                                  float* __restrict__ st) {
    const int lane = threadIdx.x & 63;
    const int w = threadIdx.x >> 6;
    const int r = blockIdx.x * 4 + w;
    const int h = r >> 12;
    const int n = r & 4095;
    float x = xp[(size_t)n * GHF + h * GF + lane];
    float s1 = x * a_src[h * GF + lane];
    float s2 = x * a_tgt[h * GF + lane];
#pragma unroll
    for (int d = 1; d < 64; d <<= 1) {
        s1 += __shfl_xor(s1, d);
        s2 += __shfl_xor(s2, d);
    }
    if (lane == 0) {
        ss[h * GN + n] = s1;
        st[h * GN + n] = s2;
    }
}

// ---------------- Kernel 3: stmax[h] = max_n st[h][n] ----------------
__global__ __launch_bounds__(512) void gat_stmax(const float* __restrict__ st,
                                                 float* __restrict__ stmax) {
    const int h = threadIdx.x >> 6;
    const int lane = threadIdx.x & 63;
    float m = -1e30f;
    for (int i = lane; i < GN; i += 64) m = fmaxf(m, st[h * GN + i]);
#pragma unroll
    for (int d = 1; d < 64; d <<= 1) m = fmaxf(m, __shfl_xor(m, d));
    if (lane == 0) stmax[h] = m;
}

// ---------------- Kernel 4: xp -> MFMA B-fragment layout, bf16 hi/lo ----------------
// frag fi = ((h*128 + t)*4 + cf); lane holds X[m = t*32 + (lane>>4)*8 + j][col = cf*16 + (lane&15)]
__global__ __launch_bounds__(256) void gat_fragconv(const float* __restrict__ xp,
                                                    short* __restrict__ bh,
                                                    short* __restrict__ bl) {
    const int idx = blockIdx.x * 256 + threadIdx.x;   // (h,t,cf,lane)
    const int lane = idx & 63;
    const int cf = (idx >> 6) & 3;
    const int t = (idx >> 8) & 127;
    const int h = idx >> 15;
    const int g = lane >> 4, c = lane & 15;
    const int col = h * GF + cf * 16 + c;
    const int m0 = t * 32 + g * 8;
    short8v vh, vl;
#pragma unroll
    for (int j = 0; j < 8; ++j) {
        float x = xp[(size_t)(m0 + j) * GHF + col];
        short hi = f2bf(x);
        vh[j] = hi;
        vl[j] = f2bf(x - bf2f(hi));
    }
    ((short8v*)bh)[idx] = vh;
    ((short8v*)bl)[idx] = vl;
}

// ---------------- Kernel 5: flash attention, MFMA, fixed softmax bound, m-split ----------------
// block = 256 thr = 4 waves; wave = head (blockIdx.y*4 + wid); 32 query rows; split s over keys.
__global__ __launch_bounds__(256) void gat_attn_mfma(const short* __restrict__ bh,
                                                     const short* __restrict__ bl,
                                                     const float* __restrict__ ss,
                                                     const float* __restrict__ st,
                                                     const float* __restrict__ stmax,
                                                     const float* __restrict__ mask,
                                                     float* __restrict__ acc_p,
                                                     float* __restrict__ l_p,
                                                     int S) {
    const int lane = threadIdx.x & 63;
    const int h = blockIdx.y * 4 + (threadIdx.x >> 6);
    const int q0 = blockIdx.x * 32;
    const int s = blockIdx.z;
    const int TPS = 128 / S;                 // 32-key tiles per split

    const int qa = q0 + (lane & 15);
    const int qb = qa + 16;
    const float ssa = ss[h * GN + qa];
    const float ssb = ss[h * GN + qb];
    const float smx = stmax[h];
    const float ca = leaky(ssa + smx);       // fixed softmax bound (>= true row max for <=0 masks)
    const float cb = leaky(ssb + smx);
    const int g = lane >> 4;

    f32x4 acc[2][4];
#pragma unroll
    for (int qf = 0; qf < 2; ++qf)
#pragma unroll
        for (int cf = 0; cf < 4; ++cf) acc[qf][cf] = (f32x4){0.f, 0.f, 0.f, 0.f};
    float lsa = 0.f, lsb = 0.f;

    for (int t = s * TPS; t < (s + 1) * TPS; ++t) {
        const int m0 = t * 32 + g * 8;
        // loads: st (8), mask rows qa/qb (8 each), B frags hi/lo (4 each)
        const float4* stp = (const float4*)&st[h * GN + m0];
        float4 st0 = stp[0], st1 = stp[1];
        const float4* mpa = (const float4*)&mask[(size_t)qa * GN + m0];
        float4 ma0 = mpa[0], ma1 = mpa[1];
        const float4* mpb = (const float4*)&mask[(size_t)qb * GN + m0];
        float4 mb0 = mpb[0], mb1 = mpb[1];
        const short8v* bhp = (const short8v*)bh + ((size_t)(h * 128 + t) * 4) * 64 + lane;
        const short8v* blp = (const short8v*)bl + ((size_t)(h * 128 + t) * 4) * 64 + lane;
        short8v Bh[4], Bl[4];
#pragma unroll
        for (int cf = 0; cf < 4; ++cf) { Bh[cf] = bhp[cf * 64]; Bl[cf] = blp[cf * 64]; }

        float stv[8] = {st0.x, st0.y, st0.z, st0.w, st1.x, st1.y, st1.z, st1.w};
        float mav[8] = {ma0.x, ma0.y, ma0.z, ma0.w, ma1.x, ma1.y, ma1.z, ma1.w};
        float mbv[8] = {mb0.x, mb0.y, mb0.z, mb0.w, mb1.x, mb1.y, mb1.z, mb1.w};

        float pa[8], pb[8];
#pragma unroll
        for (int j = 0; j < 8; ++j) {
            float ta = ssa + stv[j];
            float sa = leaky(ta) + mav[j];
            pa[j] = exp2f((sa - ca) * LOG2E);
            lsa += pa[j];
            float tb = ssb + stv[j];
            float sb = leaky(tb) + mbv[j];
            pb[j] = exp2f((sb - cb) * LOG2E);
            lsb += pb[j];
        }
        short8v pha, pla, phb, plb;
#pragma unroll
        for (int j = 0; j < 8; ++j) {
            short hia = f2bf(pa[j]);
            pha[j] = hia; pla[j] = f2bf(pa[j] - bf2f(hia));
            short hib = f2bf(pb[j]);
            phb[j] = hib; plb[j] = f2bf(pb[j] - bf2f(hib));
        }
#pragma unroll
        for (int cf = 0; cf < 4; ++cf) {
            acc[0][cf] = __builtin_amdgcn_mfma_f32_16x16x32_bf16(pha, Bh[cf], acc[0][cf], 0, 0, 0);
            acc[0][cf] = __builtin_amdgcn_mfma_f32_16x16x32_bf16(pla, Bh[cf], acc[0][cf], 0, 0, 0);
            acc[0][cf] = __builtin_amdgcn_mfma_f32_16x16x32_bf16(pha, Bl[cf], acc[0][cf], 0, 0, 0);
            acc[1][cf] = __builtin_amdgcn_mfma_f32_16x16x32_bf16(phb, Bh[cf], acc[1][cf], 0, 0, 0);
            acc[1][cf] = __builtin_amdgcn_mfma_f32_16x16x32_bf16(plb, Bh[cf], acc[1][cf], 0, 0, 0);
            acc[1][cf] = __builtin_amdgcn_mfma_f32_16x16x32_bf16(phb, Bl[cf], acc[1][cf], 0, 0, 0);
        }
    }

    // partial row-sums: combine the 4 k-groups (lanes l, l^16, l^32, l^48)
    lsa += __shfl_xor(lsa, 16); lsa += __shfl_xor(lsa, 32);
    lsb += __shfl_xor(lsb, 16); lsb += __shfl_xor(lsb, 32);
    if (lane < 16) {
        l_p[(size_t)(s * GH + h) * GN + qa] = lsa;
        l_p[(size_t)(s * GH + h) * GN + qb] = lsb;
    }
    // store partial acc: D layout col=lane&15, row=(lane>>4)*4+r
#pragma unroll
    for (int qf = 0; qf < 2; ++qf)
#pragma unroll
        for (int cf = 0; cf < 4; ++cf)
#pragma unroll
            for (int r = 0; r < 4; ++r) {
                int row = q0 + qf * 16 + (lane >> 4) * 4 + r;
                int col = cf * 16 + (lane & 15);
                acc_p[((size_t)(s * GH + h) * GN + row) * GF + col] = acc[qf][cf][r];
            }
}

// ---------------- Kernel 6: combine splits, head-mean, relu ----------------
__global__ __launch_bounds__(256) void gat_combine(const float* __restrict__ acc_p,
                                                   const float* __restrict__ l_p,
                                                   float* __restrict__ out, int S) {
    const int idx = blockIdx.x * 256 + threadIdx.x;    // n*64 + f
    const int n = idx >> 6, f = idx & 63;
    float r = 0.f;
#pragma unroll
    for (int h = 0; h < GH; ++h) {
        float a = 0.f, l = 0.f;
        for (int s = 0; s < S; ++s) {
            a += acc_p[((size_t)(s * GH + h) * GN + n) * GF + f];
            l += l_p[(size_t)(s * GH + h) * GN + n];
        }
        r += a / l;
    }
    out[idx] = fmaxf(r * 0.125f, 0.f);
}

extern "C" void kernel_launch(void* const* d_in, const int* in_sizes, int n_in,
                              void* d_out, int out_size, void* d_ws, size_t ws_size,
                              hipStream_t stream) {
    const float* A     = (const float*)d_in[0];
    const float* mask  = (const float*)d_in[1];
    const float* Wp    = (const float*)d_in[2];
    const float* a_src = (const float*)d_in[3];
    const float* a_tgt = (const float*)d_in[4];
    float* out = (float*)d_out;

    char* w = (char*)d_ws;
    float* xp    = (float*)w;              w += (size_t)GN * GHF * 4;        // 8 MB
    float* ss    = (float*)w;              w += (size_t)GH * GN * 4;
    float* st    = (float*)w;              w += (size_t)GH * GN * 4;
    float* stmx  = (float*)w;              w += 256;
    short* bh    = (short*)w;              w += (size_t)GH * 128 * 4 * 64 * 8 * 2; // 4 MB
    short* bl    = (short*)w;              w += (size_t)GH * 128 * 4 * 64 * 8 * 2; // 4 MB
    size_t base = (size_t)(w - (char*)d_ws);
    size_t per_s = (size_t)GH * GN * GF * 4 + (size_t)GH * GN * 4;           // 8.5 MB
    int S = 4;
    while (S > 1 && base + (size_t)S * per_s > ws_size) S >>= 1;
    float* acc_p = (float*)w;              w += (size_t)S * GH * GN * GF * 4;
    float* l_p   = (float*)w;

    gat_proj<<<dim3(GN / 64, GHF / 64), 256, 0, stream>>>(A, Wp, xp);
    gat_scores<<<(GH * GN) / 4, 256, 0, stream>>>(xp, a_src, a_tgt, ss, st);
    gat_stmax<<<1, 512, 0, stream>>>(st, stmx);
    gat_fragconv<<<(GH * 128 * 4 * 64) / 256, 256, 0, stream>>>(xp, bh, bl);
    gat_attn_mfma<<<dim3(GN / 32, 2, S), 256, 0, stream>>>(bh, bl, ss, st, stmx, mask,
                                                           acc_p, l_p, S);
    gat_combine<<<(GN * GF) / 256, 256, 0, stream>>>(acc_p, l_p, out, S);
}